// Round 8
// baseline (174.642 us; speedup 1.0000x reference)
//
#include <hip/hip_runtime.h>
#include <hip/hip_bf16.h>

#define B_SZ   2
#define C_CH   64
#define NQ     8          // q/k real channels (C/8)
#define QKS    16         // q/k stored stride (zero-padded to MFMA K)
#define NPIX   9216       // 96*96
#define NKS    576        // NPIX/16 key 16-slices per batch
#define QBLKS  288        // NPIX/32 query blocks (32 queries per block)
#define KPART  4          // key partitions, one per wave in a block
#define KEYS_P 2304       // NPIX/KPART
#define NCHUNK 36         // 64 keys per chunk
#define SM_F   2080       // per-slot combine floats: 2048 O + 32 L (2 slots)
#define NP4    2304       // NPIX/4
#define KSTEP2 1024       // kp elements per 64-key chunk (64*16)
#define VSTEP  4096       // vswz elements per chunk (4 kslices x 2 ctiles x 512)

typedef short bf16x8 __attribute__((ext_vector_type(8)));
typedef float f32x4  __attribute__((ext_vector_type(4)));
typedef float f32x16 __attribute__((ext_vector_type(16)));
typedef unsigned u32x4 __attribute__((ext_vector_type(4)));
typedef unsigned uint2v __attribute__((ext_vector_type(2)));

// single-instruction packed f32->bf16 (RNE), a -> low16, b -> high16
static __device__ __forceinline__ unsigned pack2bf(float a, float b){
    unsigned r;
    asm("v_cvt_pk_bf16_f32 %0, %1, %2" : "=v"(r) : "v"(a), "v"(b));
    return r;
}

// raw v_exp_f32 (2^x). Inputs here are bounded QK scores — no denormal fixup needed.
static __device__ __forceinline__ float exp2r(float x){
    return __builtin_amdgcn_exp2f(x);
}

// ---------- fused prep, 8-channel register blocking (unchanged) ----------
__global__ __launch_bounds__(256) void prep_kernel(
    const float* __restrict__ x,
    const float* __restrict__ wq, const float* __restrict__ bq,
    const float* __restrict__ wk, const float* __restrict__ bk,
    const float* __restrict__ wv, const float* __restrict__ bv,
    __hip_bfloat16* __restrict__ qp, __hip_bfloat16* __restrict__ kp,
    __hip_bfloat16* __restrict__ vswz, float* __restrict__ amean)
{
    const int blk = blockIdx.x, tid = threadIdx.x;
    if (blk < 144){
        int t  = blk*256 + tid;            // (b, c8, n4)
        int n  = (t % NP4) * 4;
        int c8 = (t / NP4) & 7;            // wave-uniform (NP4 % 64 == 0)
        int b  = t / (NP4*8);
        c8 = __builtin_amdgcn_readfirstlane(c8);
        b  = __builtin_amdgcn_readfirstlane(b);
        float acc[8][4];
#pragma unroll
        for (int k = 0; k < 8; ++k){
            float bvv = bv[c8*8 + k];
            acc[k][0] = bvv; acc[k][1] = bvv; acc[k][2] = bvv; acc[k][3] = bvv;
        }
#pragma unroll 4
        for (int ci = 0; ci < C_CH; ++ci){
            const float4 xv = *reinterpret_cast<const float4*>(
                x + (size_t)(b*C_CH + ci)*NPIX + n);
#pragma unroll
            for (int k = 0; k < 8; ++k){
                float w = wv[(c8*8 + k)*C_CH + ci];
                acc[k][0] = fmaf(xv.x, w, acc[k][0]);
                acc[k][1] = fmaf(xv.y, w, acc[k][1]);
                acc[k][2] = fmaf(xv.z, w, acc[k][2]);
                acc[k][3] = fmaf(xv.w, w, acc[k][3]);
            }
        }
#pragma unroll
        for (int k = 0; k < 8; ++k){
            int c = c8*8 + k;
            size_t base = ((size_t)((b*NKS + (n >> 4))*2 + (c >> 5)))*512
                        + (((n >> 3) & 1) << 8) + ((c & 31) << 3) + (n & 7);
            unsigned long long wpk =
                (unsigned long long)pack2bf(acc[k][0], acc[k][1]) |
                ((unsigned long long)pack2bf(acc[k][2], acc[k][3]) << 32);
            *reinterpret_cast<unsigned long long*>(vswz + base) = wpk;
        }
    } else if (blk < 180){
        int t  = (blk - 144)*256 + tid;    // (b, o8, n4)
        int n  = (t % NP4) * 4;
        int o8 = (t / NP4) & 1;            // wave-uniform; 0 => q, 1 => k
        int b  = t / (NP4*2);
        o8 = __builtin_amdgcn_readfirstlane(o8);
        b  = __builtin_amdgcn_readfirstlane(b);
        const bool isq = (o8 == 0);
        const float* w    = isq ? wq : wk;
        const float* bias = isq ? bq : bk;
        float acc[8][4];
#pragma unroll
        for (int k = 0; k < 8; ++k){
            float bb = bias[k];
            acc[k][0] = bb; acc[k][1] = bb; acc[k][2] = bb; acc[k][3] = bb;
        }
#pragma unroll 4
        for (int ci = 0; ci < C_CH; ++ci){
            const float4 xv = *reinterpret_cast<const float4*>(
                x + (size_t)(b*C_CH + ci)*NPIX + n);
#pragma unroll
            for (int k = 0; k < 8; ++k){
                float wv_ = w[k*C_CH + ci];
                acc[k][0] = fmaf(xv.x, wv_, acc[k][0]);
                acc[k][1] = fmaf(xv.y, wv_, acc[k][1]);
                acc[k][2] = fmaf(xv.z, wv_, acc[k][2]);
                acc[k][3] = fmaf(xv.w, wv_, acc[k][3]);
            }
        }
        if (isq){  // fold log2(e) so softmax uses native exp2
#pragma unroll
            for (int k = 0; k < 8; ++k)
#pragma unroll
                for (int px = 0; px < 4; ++px) acc[k][px] *= 1.44269504f;
        }
        __hip_bfloat16* dst = isq ? qp : kp;
        u32x4 zr; zr[0] = 0; zr[1] = 0; zr[2] = 0; zr[3] = 0;
#pragma unroll
        for (int px = 0; px < 4; ++px){
            u32x4 row;
            row[0] = pack2bf(acc[0][px], acc[1][px]);
            row[1] = pack2bf(acc[2][px], acc[3][px]);
            row[2] = pack2bf(acc[4][px], acc[5][px]);
            row[3] = pack2bf(acc[6][px], acc[7][px]);
            __hip_bfloat16* d0 = dst + ((size_t)(b*NPIX + n + px))*QKS;
            *reinterpret_cast<u32x4*>(d0)     = row;
            *reinterpret_cast<u32x4*>(d0 + 8) = zr;   // zero pad dims 8..15
        }
    } else {
        int bc = blk - 180;                // (b*64+c)
        float s = 0.f;
        for (int i = tid; i < NPIX; i += 256) s += x[(size_t)bc*NPIX + i];
#pragma unroll
        for (int o = 32; o > 0; o >>= 1) s += __shfl_down(s, o, 64);
        __shared__ float red[4];
        if ((tid & 63) == 0) red[tid >> 6] = s;
        __syncthreads();
        if (tid == 0) amean[bc] = (red[0] + red[1] + red[2] + red[3]) * (1.f / (float)NPIX);
    }
}

// ---------- fused attention: 32x32x16 MFMA, K+V double-buffered one chunk ahead ----------
__global__ __launch_bounds__(256) void flash_fused(
    const __hip_bfloat16* __restrict__ qp,
    const __hip_bfloat16* __restrict__ kp,
    const __hip_bfloat16* __restrict__ vswz,
    const float* __restrict__ amean,
    const float* __restrict__ sw1, const float* __restrict__ sb1,
    const float* __restrict__ s1w, const float* __restrict__ s1b,
    const float* __restrict__ s1m, const float* __restrict__ s1v,
    const float* __restrict__ sw2, const float* __restrict__ sb2,
    const float* __restrict__ s2w, const float* __restrict__ s2b,
    const float* __restrict__ s2m, const float* __restrict__ s2v,
    const float* __restrict__ x,
    const float* __restrict__ gamma,
    const float* __restrict__ bnw, const float* __restrict__ bnb,
    const float* __restrict__ bnm, const float* __restrict__ bnv,
    float* __restrict__ out)
{
    __shared__ __align__(16) float sm[2*SM_F];   // 16640 B: 2 combine slots

    const int qt2 = blockIdx.x, b = blockIdx.y;   // 32 queries per block
    const int p  = threadIdx.x >> 6;     // wave = key partition (0..3)
    const int l  = threadIdx.x & 63;
    const int lc = l & 31;               // column lane (query / channel)
    const int lh = l >> 5;               // lane half (k-elem group)

    // Q fragment: B-operand, B[k=(lh*8+e)][col=query lc]; pad dims read zeros
    bf16x8 qfrag = *reinterpret_cast<const bf16x8*>(
        qp + ((size_t)(b*NPIX + qt2*32 + lc))*QKS + lh*8);

    bf16x8 ones;          // bf16 1.0 x8 — A-frag for the L-denominator MFMA
#pragma unroll
    for (int i = 0; i < 8; ++i) ones[i] = (short)0x3F80;

    f32x16 zero16;
#pragma unroll
    for (int i = 0; i < 16; ++i) zero16[i] = 0.f;

    f32x16 Of0 = zero16, Of1 = zero16;   // O^T accum: [channel row][query col], 2 ctiles
    f32x16 Lacc = zero16;                // L accum (all rows identical)

    // running pointers
    const __hip_bfloat16* kptr = kp + ((size_t)(b*NPIX + p*KEYS_P + lc))*QKS + lh*8;
    const __hip_bfloat16* vptr = vswz + ((size_t)((b*NKS + p*(KEYS_P/16))*2))*512 + l*8;

    bf16x8 kA0, kA1, kB0, kB1;
    bf16x8 vfA[8], vfB[8];

    auto loadK = [&](bf16x8& d0, bf16x8& d1){
        d0 = *reinterpret_cast<const bf16x8*>(kptr);
        d1 = *reinterpret_cast<const bf16x8*>(kptr + 512);
        kptr += KSTEP2;
    };
    auto loadV = [&](bf16x8 (&dst)[8]){
#pragma unroll
        for (int t = 0; t < 8; ++t)
            dst[t] = *reinterpret_cast<const bf16x8*>(vptr + t*512);
        vptr += VSTEP;
    };
    auto compute = [&](const bf16x8& k0, const bf16x8& k1, const bf16x8 (&vf)[8]){
        // QK^T per 32-key tile; P = exp2(S) via raw v_exp_f32; cvt_pk row pairs
        unsigned D[16];
#pragma unroll
        for (int kt = 0; kt < 2; ++kt){
            f32x16 s = __builtin_amdgcn_mfma_f32_32x32x16_bf16(
                kt ? k1 : k0, qfrag, zero16, 0, 0, 0);
#pragma unroll
            for (int g = 0; g < 4; ++g){
                float e0 = exp2r(s[4*g+0]), e1 = exp2r(s[4*g+1]);
                float e2 = exp2r(s[4*g+2]), e3 = exp2r(s[4*g+3]);
                D[kt*8 + g*2 + 0] = pack2bf(e0, e1);
                D[kt*8 + g*2 + 1] = pack2bf(e2, e3);
            }
        }
        // per 16-key slice: build PV B-frag with 2 permlane32_swaps, then MFMA
        __builtin_amdgcn_s_setprio(1);
#pragma unroll
        for (int ks = 0; ks < 4; ++ks){
            const int base = (ks >> 1)*8 + (ks & 1)*4;
            uint2v r0 = __builtin_amdgcn_permlane32_swap(D[base+0], D[base+2], false, false);
            uint2v r1 = __builtin_amdgcn_permlane32_swap(D[base+1], D[base+3], false, false);
            u32x4 pu; pu[0] = r0[0]; pu[1] = r1[0]; pu[2] = r0[1]; pu[3] = r1[1];
            bf16x8 pf = __builtin_bit_cast(bf16x8, pu);
            Of0  = __builtin_amdgcn_mfma_f32_32x32x16_bf16(vf[ks*2+0], pf, Of0, 0, 0, 0);
            Of1  = __builtin_amdgcn_mfma_f32_32x32x16_bf16(vf[ks*2+1], pf, Of1, 0, 0, 0);
            Lacc = __builtin_amdgcn_mfma_f32_32x32x16_bf16(ones,       pf, Lacc, 0, 0, 0);
        }
        __builtin_amdgcn_s_setprio(0);
    };

    // prologue: chunk 0 into A
    loadK(kA0, kA1); loadV(vfA);
    // 17 iterations cover chunks 0..33 (prefetch through chunk 34)
    for (int it = 0; it < 17; ++it){
        loadK(kB0, kB1); loadV(vfB);    // chunk 2it+1
        compute(kA0, kA1, vfA);         // chunk 2it
        loadK(kA0, kA1); loadV(vfA);    // chunk 2it+2
        compute(kB0, kB1, vfB);         // chunk 2it+1
    }
    // tail: chunk 34 in A; load+compute 35
    loadK(kB0, kB1); loadV(vfB);
    compute(kA0, kA1, vfA);
    compute(kB0, kB1, vfB);

    // --- SE a1 (after hot loop; only needs amean) ---
    float a1r;
    {
        int r8 = l & 7;
        float s = sb1[r8];
#pragma unroll 8
        for (int c = 0; c < C_CH; ++c)
            s = fmaf(amean[b*C_CH + c], sw1[r8*C_CH + c], s);
        s = (s - s1m[r8]) * (s1w[r8] * rsqrtf(s1v[r8] + 1e-5f)) + s1b[r8];
        a1r = fmaxf(s, 0.f);
    }

    // --- 2-slot tree combine: waves 2,3 write slots 0,1; waves 0,1 accumulate ---
    if (p >= 2){
        const int ps = p - 2;
#pragma unroll
        for (int r = 0; r < 16; ++r){
            sm[ps*SM_F +        r*64 + l] = Of0[r];
            sm[ps*SM_F + 1024 + r*64 + l] = Of1[r];
        }
        if (l < 32) sm[ps*SM_F + 2048 + l] = Lacc[0];
    }
    __syncthreads();
    if (p < 2){
#pragma unroll
        for (int r = 0; r < 16; ++r){
            sm[p*SM_F +        r*64 + l] += Of0[r];
            sm[p*SM_F + 1024 + r*64 + l] += Of1[r];
        }
        if (l < 32) sm[p*SM_F + 2048 + l] += Lacc[0];
    }
    __syncthreads();

    // --- combine 2 slots + SE a2 + epilogue: out = x*(1+a2) + BN(gamma*O/L) ---
    {
        const int i   = lc;                // query
        const int cgs = p*2 + lh;          // channel group (0..7), 8 channels each
        float gam = gamma[0];

        // SE a2 gather a1 via shuffles
        float a1g[8];
#pragma unroll
        for (int j = 0; j < 8; ++j) a1g[j] = __shfl(a1r, (l & 56) | j, 64);

        float L = sm[2048 + i] + sm[SM_F + 2048 + i];
        float invL = 1.f / L;
        int n = qt2*32 + i;
#pragma unroll
        for (int r = 0; r < 8; ++r){
            int c = cgs*8 + r;
            float s = sb2[c];
#pragma unroll
            for (int j = 0; j < 8; ++j) s = fmaf(a1g[j], sw2[c*NQ + j], s);
            s = (s - s2m[c]) * (s2w[c] * rsqrtf(s2v[c] + 1e-5f)) + s2b[c];
            float a2v = fmaxf(s, 0.f);

            // channel -> (ctile, reg, lane-half) in the 32x32 C layout
            int c5   = c & 31;
            int reg  = (c5 & 3) + 4*(c5 >> 3);
            int lsrc = (c5 >> 2) & 1;
            int o    = (c >> 5)*1024 + reg*64 + lsrc*32 + i;
            float O = sm[o] + sm[SM_F + o];
            float pam = gam * O * invL;
            pam = (pam - bnm[c]) * (bnw[c] * rsqrtf(bnv[c] + 1e-5f)) + bnb[c];
            float xv = x[(size_t)(b*C_CH + c)*NPIX + n];
            out[(size_t)(b*C_CH + c)*NPIX + n] = fmaf(xv, a2v, xv + pam);
        }
    }
}

extern "C" void kernel_launch(void* const* d_in, const int* in_sizes, int n_in,
                              void* d_out, int out_size, void* d_ws, size_t ws_size,
                              hipStream_t stream)
{
    const float* x     = (const float*)d_in[0];
    const float* wq    = (const float*)d_in[1];
    const float* bq    = (const float*)d_in[2];
    const float* wk    = (const float*)d_in[3];
    const float* bk    = (const float*)d_in[4];
    const float* wv    = (const float*)d_in[5];
    const float* bv    = (const float*)d_in[6];
    const float* gamma = (const float*)d_in[7];
    const float* bnw   = (const float*)d_in[8];
    const float* bnb   = (const float*)d_in[9];
    const float* bnm   = (const float*)d_in[10];
    const float* bnv   = (const float*)d_in[11];
    const float* sw1   = (const float*)d_in[12];
    const float* sb1   = (const float*)d_in[13];
    const float* s1w   = (const float*)d_in[14];
    const float* s1b   = (const float*)d_in[15];
    const float* s1m   = (const float*)d_in[16];
    const float* s1v   = (const float*)d_in[17];
    const float* sw2   = (const float*)d_in[18];
    const float* sb2   = (const float*)d_in[19];
    const float* s2w   = (const float*)d_in[20];
    const float* s2b   = (const float*)d_in[21];
    const float* s2m   = (const float*)d_in[22];
    const float* s2v   = (const float*)d_in[23];

    size_t off = 0;
    auto give = [&](size_t bytes) -> void* {
        void* r = (char*)d_ws + off;
        off += (bytes + 255) & ~(size_t)255;
        return r;
    };
    __hip_bfloat16* qp   = (__hip_bfloat16*)give((size_t)B_SZ*NPIX*QKS*2);
    __hip_bfloat16* kp   = (__hip_bfloat16*)give((size_t)B_SZ*NPIX*QKS*2);
    __hip_bfloat16* vswz = (__hip_bfloat16*)give((size_t)B_SZ*C_CH*NPIX*2);
    float* amean = (float*)give((size_t)B_SZ*C_CH*4);

    prep_kernel<<<dim3(308), dim3(256), 0, stream>>>(x, wq, bq, wk, bk, wv, bv,
                                                     qp, kp, vswz, amean);
    flash_fused<<<dim3(QBLKS, B_SZ), dim3(256), 0, stream>>>(
        qp, kp, vswz, amean,
        sw1, sb1, s1w, s1b, s1m, s1v,
        sw2, sb2, s2w, s2b, s2m, s2v,
        x, gamma, bnw, bnb, bnm, bnv, (float*)d_out);
}

// Round 9
// 171.326 us; speedup vs baseline: 1.0194x; 1.0194x over previous
//
#include <hip/hip_runtime.h>
#include <hip/hip_bf16.h>

#define B_SZ   2
#define C_CH   64
#define NQ     8          // q/k real channels (C/8)
#define QKS    16         // q/k stored stride (zero-padded to MFMA K)
#define NPIX   9216       // 96*96
#define NKS    576        // NPIX/16 key 16-slices per batch
#define QBLKS  288        // NPIX/32 query blocks (32 queries per block)
#define KPART  4          // key partitions, one per wave in a block
#define NSPLIT 4          // key splits across blockIdx.z
#define KEYS_W 576        // keys per wave = NPIX/(NSPLIT*KPART)
#define NCHUNK_W 9        // 64-key chunks per wave
#define SM_F   2080       // per-slot combine floats: 2048 O + 32 L (2 slots)
#define PSLOT  2080       // partial slot floats
#define NP4    2304       // NPIX/4
#define KSTEP2 1024       // kp elements per 64-key chunk (64*16)
#define VSTEP  4096       // vswz elements per chunk (4 kslices x 2 ctiles x 512)

typedef short bf16x8 __attribute__((ext_vector_type(8)));
typedef float f32x4  __attribute__((ext_vector_type(4)));
typedef float f32x16 __attribute__((ext_vector_type(16)));
typedef unsigned u32x4 __attribute__((ext_vector_type(4)));
typedef unsigned uint2v __attribute__((ext_vector_type(2)));

// single-instruction packed f32->bf16 (RNE), a -> low16, b -> high16
static __device__ __forceinline__ unsigned pack2bf(float a, float b){
    unsigned r;
    asm("v_cvt_pk_bf16_f32 %0, %1, %2" : "=v"(r) : "v"(a), "v"(b));
    return r;
}

// raw v_exp_f32 (2^x). Inputs here are bounded QK scores — no denormal fixup needed.
static __device__ __forceinline__ float exp2r(float x){
    return __builtin_amdgcn_exp2f(x);
}

// ---------- fused prep, 8-channel register blocking (unchanged) ----------
__global__ __launch_bounds__(256) void prep_kernel(
    const float* __restrict__ x,
    const float* __restrict__ wq, const float* __restrict__ bq,
    const float* __restrict__ wk, const float* __restrict__ bk,
    const float* __restrict__ wv, const float* __restrict__ bv,
    __hip_bfloat16* __restrict__ qp, __hip_bfloat16* __restrict__ kp,
    __hip_bfloat16* __restrict__ vswz, float* __restrict__ amean)
{
    const int blk = blockIdx.x, tid = threadIdx.x;
    if (blk < 144){
        int t  = blk*256 + tid;            // (b, c8, n4)
        int n  = (t % NP4) * 4;
        int c8 = (t / NP4) & 7;            // wave-uniform (NP4 % 64 == 0)
        int b  = t / (NP4*8);
        c8 = __builtin_amdgcn_readfirstlane(c8);
        b  = __builtin_amdgcn_readfirstlane(b);
        float acc[8][4];
#pragma unroll
        for (int k = 0; k < 8; ++k){
            float bvv = bv[c8*8 + k];
            acc[k][0] = bvv; acc[k][1] = bvv; acc[k][2] = bvv; acc[k][3] = bvv;
        }
#pragma unroll 4
        for (int ci = 0; ci < C_CH; ++ci){
            const float4 xv = *reinterpret_cast<const float4*>(
                x + (size_t)(b*C_CH + ci)*NPIX + n);
#pragma unroll
            for (int k = 0; k < 8; ++k){
                float w = wv[(c8*8 + k)*C_CH + ci];
                acc[k][0] = fmaf(xv.x, w, acc[k][0]);
                acc[k][1] = fmaf(xv.y, w, acc[k][1]);
                acc[k][2] = fmaf(xv.z, w, acc[k][2]);
                acc[k][3] = fmaf(xv.w, w, acc[k][3]);
            }
        }
#pragma unroll
        for (int k = 0; k < 8; ++k){
            int c = c8*8 + k;
            size_t base = ((size_t)((b*NKS + (n >> 4))*2 + (c >> 5)))*512
                        + (((n >> 3) & 1) << 8) + ((c & 31) << 3) + (n & 7);
            unsigned long long wpk =
                (unsigned long long)pack2bf(acc[k][0], acc[k][1]) |
                ((unsigned long long)pack2bf(acc[k][2], acc[k][3]) << 32);
            *reinterpret_cast<unsigned long long*>(vswz + base) = wpk;
        }
    } else if (blk < 180){
        int t  = (blk - 144)*256 + tid;    // (b, o8, n4)
        int n  = (t % NP4) * 4;
        int o8 = (t / NP4) & 1;            // wave-uniform; 0 => q, 1 => k
        int b  = t / (NP4*2);
        o8 = __builtin_amdgcn_readfirstlane(o8);
        b  = __builtin_amdgcn_readfirstlane(b);
        const bool isq = (o8 == 0);
        const float* w    = isq ? wq : wk;
        const float* bias = isq ? bq : bk;
        float acc[8][4];
#pragma unroll
        for (int k = 0; k < 8; ++k){
            float bb = bias[k];
            acc[k][0] = bb; acc[k][1] = bb; acc[k][2] = bb; acc[k][3] = bb;
        }
#pragma unroll 4
        for (int ci = 0; ci < C_CH; ++ci){
            const float4 xv = *reinterpret_cast<const float4*>(
                x + (size_t)(b*C_CH + ci)*NPIX + n);
#pragma unroll
            for (int k = 0; k < 8; ++k){
                float wv_ = w[k*C_CH + ci];
                acc[k][0] = fmaf(xv.x, wv_, acc[k][0]);
                acc[k][1] = fmaf(xv.y, wv_, acc[k][1]);
                acc[k][2] = fmaf(xv.z, wv_, acc[k][2]);
                acc[k][3] = fmaf(xv.w, wv_, acc[k][3]);
            }
        }
        if (isq){  // fold log2(e) so softmax uses native exp2
#pragma unroll
            for (int k = 0; k < 8; ++k)
#pragma unroll
                for (int px = 0; px < 4; ++px) acc[k][px] *= 1.44269504f;
        }
        __hip_bfloat16* dst = isq ? qp : kp;
        u32x4 zr; zr[0] = 0; zr[1] = 0; zr[2] = 0; zr[3] = 0;
#pragma unroll
        for (int px = 0; px < 4; ++px){
            u32x4 row;
            row[0] = pack2bf(acc[0][px], acc[1][px]);
            row[1] = pack2bf(acc[2][px], acc[3][px]);
            row[2] = pack2bf(acc[4][px], acc[5][px]);
            row[3] = pack2bf(acc[6][px], acc[7][px]);
            __hip_bfloat16* d0 = dst + ((size_t)(b*NPIX + n + px))*QKS;
            *reinterpret_cast<u32x4*>(d0)     = row;
            *reinterpret_cast<u32x4*>(d0 + 8) = zr;   // zero pad dims 8..15
        }
    } else {
        int bc = blk - 180;                // (b*64+c)
        float s = 0.f;
        for (int i = tid; i < NPIX; i += 256) s += x[(size_t)bc*NPIX + i];
#pragma unroll
        for (int o = 32; o > 0; o >>= 1) s += __shfl_down(s, o, 64);
        __shared__ float red[4];
        if ((tid & 63) == 0) red[tid >> 6] = s;
        __syncthreads();
        if (tid == 0) amean[bc] = (red[0] + red[1] + red[2] + red[3]) * (1.f / (float)NPIX);
    }
}

// ---------- attention partial: 32x32x16 MFMA, key-split x4, r6 compute body ----------
__global__ __launch_bounds__(256) void flash_fused(
    const __hip_bfloat16* __restrict__ qp,
    const __hip_bfloat16* __restrict__ kp,
    const __hip_bfloat16* __restrict__ vswz,
    float* __restrict__ pws)
{
    __shared__ __align__(16) float sm[2*SM_F];   // 16640 B: 2 combine slots

    const int qt2 = blockIdx.x, b = blockIdx.y, z = blockIdx.z;
    const int p  = threadIdx.x >> 6;     // wave = key sub-partition (0..3)
    const int l  = threadIdx.x & 63;
    const int lc = l & 31;               // column lane (query / channel)
    const int lh = l >> 5;               // lane half (k-elem group)

    // Q fragment: B-operand, B[k=(lh*8+e)][col=query lc]; pad dims read zeros
    bf16x8 qfrag = *reinterpret_cast<const bf16x8*>(
        qp + ((size_t)(b*NPIX + qt2*32 + lc))*QKS + lh*8);

    bf16x8 ones;          // bf16 1.0 x8 — A-frag for the L-denominator MFMA
#pragma unroll
    for (int i = 0; i < 8; ++i) ones[i] = (short)0x3F80;

    f32x16 zero16;
#pragma unroll
    for (int i = 0; i < 16; ++i) zero16[i] = 0.f;

    f32x16 Of0 = zero16, Of1 = zero16;   // O^T accum: [channel row][query col], 2 ctiles
    f32x16 Lacc = zero16;                // L accum (all rows identical)

    // running pointers for this wave's key range
    const int kpart = z*KPART + p;       // 0..15, each 576 keys
    const __hip_bfloat16* kptr = kp + ((size_t)(b*NPIX + kpart*KEYS_W + lc))*QKS + lh*8;
    const __hip_bfloat16* vptr = vswz + ((size_t)((b*NKS + kpart*(KEYS_W/16))*2))*512 + l*8;

    auto CHUNK = [&](const bf16x8& k0, const bf16x8& k1){
        // V tiles for this chunk (issued first; consumed after QK+exp2 — self-hiding)
        bf16x8 vf[8];
#pragma unroll
        for (int t = 0; t < 8; ++t)
            vf[t] = *reinterpret_cast<const bf16x8*>(vptr + t*512);
        vptr += VSTEP;

        // QK^T per 32-key tile; P = exp2(S) via raw v_exp_f32; cvt_pk row pairs
        unsigned D[16];
#pragma unroll
        for (int kt = 0; kt < 2; ++kt){
            f32x16 s = __builtin_amdgcn_mfma_f32_32x32x16_bf16(
                kt ? k1 : k0, qfrag, zero16, 0, 0, 0);
#pragma unroll
            for (int g = 0; g < 4; ++g){
                float e0 = exp2r(s[4*g+0]), e1 = exp2r(s[4*g+1]);
                float e2 = exp2r(s[4*g+2]), e3 = exp2r(s[4*g+3]);
                D[kt*8 + g*2 + 0] = pack2bf(e0, e1);
                D[kt*8 + g*2 + 1] = pack2bf(e2, e3);
            }
        }
        // per 16-key slice: build PV B-frag with 2 permlane32_swaps, then MFMA
        __builtin_amdgcn_s_setprio(1);
#pragma unroll
        for (int ks = 0; ks < 4; ++ks){
            const int base = (ks >> 1)*8 + (ks & 1)*4;
            uint2v r0 = __builtin_amdgcn_permlane32_swap(D[base+0], D[base+2], false, false);
            uint2v r1 = __builtin_amdgcn_permlane32_swap(D[base+1], D[base+3], false, false);
            u32x4 pu; pu[0] = r0[0]; pu[1] = r1[0]; pu[2] = r0[1]; pu[3] = r1[1];
            bf16x8 pf = __builtin_bit_cast(bf16x8, pu);
            Of0  = __builtin_amdgcn_mfma_f32_32x32x16_bf16(vf[ks*2+0], pf, Of0, 0, 0, 0);
            Of1  = __builtin_amdgcn_mfma_f32_32x32x16_bf16(vf[ks*2+1], pf, Of1, 0, 0, 0);
            Lacc = __builtin_amdgcn_mfma_f32_32x32x16_bf16(ones,       pf, Lacc, 0, 0, 0);
        }
        __builtin_amdgcn_s_setprio(0);
    };

    // K ping-pong over 9 chunks
    bf16x8 kA0, kA1, kB0, kB1;
    kA0 = *reinterpret_cast<const bf16x8*>(kptr);
    kA1 = *reinterpret_cast<const bf16x8*>(kptr + 512);
    kptr += KSTEP2;
    for (int it = 0; it < 4; ++it){
        kB0 = *reinterpret_cast<const bf16x8*>(kptr);
        kB1 = *reinterpret_cast<const bf16x8*>(kptr + 512);
        kptr += KSTEP2;
        CHUNK(kA0, kA1);                 // chunk 2it
        if (it < 3){
            kA0 = *reinterpret_cast<const bf16x8*>(kptr);
            kA1 = *reinterpret_cast<const bf16x8*>(kptr + 512);
            kptr += KSTEP2;
        } else {
            kA0 = *reinterpret_cast<const bf16x8*>(kptr);   // chunk 8 (last)
            kA1 = *reinterpret_cast<const bf16x8*>(kptr + 512);
        }
        CHUNK(kB0, kB1);                 // chunk 2it+1
    }
    CHUNK(kA0, kA1);                     // chunk 8

    // --- 2-slot tree combine: waves 2,3 write slots 0,1; waves 0,1 accumulate ---
    if (p >= 2){
        const int ps = p - 2;
#pragma unroll
        for (int r = 0; r < 16; ++r){
            sm[ps*SM_F +        r*64 + l] = Of0[r];
            sm[ps*SM_F + 1024 + r*64 + l] = Of1[r];
        }
        if (l < 32) sm[ps*SM_F + 2048 + l] = Lacc[0];
    }
    __syncthreads();
    if (p < 2){
#pragma unroll
        for (int r = 0; r < 16; ++r){
            sm[p*SM_F +        r*64 + l] += Of0[r];
            sm[p*SM_F + 1024 + r*64 + l] += Of1[r];
        }
        if (l < 32) sm[p*SM_F + 2048 + l] += Lacc[0];
    }
    __syncthreads();

    // --- write block partial (slot0 + slot1) to workspace ---
    {
        float* dst = pws + ((size_t)((b*QBLKS + qt2)*NSPLIT + z))*PSLOT;
        for (int i = threadIdx.x; i < PSLOT; i += 256)
            dst[i] = sm[i] + sm[SM_F + i];
    }
}

// ---------- combine 4 key-split partials + SE + BN epilogue ----------
__global__ __launch_bounds__(256) void combine_kernel(
    const float* __restrict__ pws,
    const float* __restrict__ amean,
    const float* __restrict__ sw1, const float* __restrict__ sb1,
    const float* __restrict__ s1w, const float* __restrict__ s1b,
    const float* __restrict__ s1m, const float* __restrict__ s1v,
    const float* __restrict__ sw2, const float* __restrict__ sb2,
    const float* __restrict__ s2w, const float* __restrict__ s2b,
    const float* __restrict__ s2m, const float* __restrict__ s2v,
    const float* __restrict__ x,
    const float* __restrict__ gamma,
    const float* __restrict__ bnw, const float* __restrict__ bnb,
    const float* __restrict__ bnm, const float* __restrict__ bnv,
    float* __restrict__ out)
{
    const int qt2 = blockIdx.x, b = blockIdx.y;
    const int p  = threadIdx.x >> 6;
    const int l  = threadIdx.x & 63;
    const int lc = l & 31;
    const int lh = l >> 5;

    // SE a1 (per-thread; lanes hold r8 = l&7)
    float a1r;
    {
        int r8 = l & 7;
        float s = sb1[r8];
#pragma unroll 8
        for (int c = 0; c < C_CH; ++c)
            s = fmaf(amean[b*C_CH + c], sw1[r8*C_CH + c], s);
        s = (s - s1m[r8]) * (s1w[r8] * rsqrtf(s1v[r8] + 1e-5f)) + s1b[r8];
        a1r = fmaxf(s, 0.f);
    }

    const float* P0 = pws + ((size_t)((b*QBLKS + qt2)*NSPLIT))*PSLOT;

    const int i   = lc;                // query
    const int cgs = p*2 + lh;          // channel group (0..7), 8 channels each
    float gam = gamma[0];

    float a1g[8];
#pragma unroll
    for (int j = 0; j < 8; ++j) a1g[j] = __shfl(a1r, (l & 56) | j, 64);

    float L = 0.f;
#pragma unroll
    for (int zz = 0; zz < NSPLIT; ++zz) L += P0[zz*PSLOT + 2048 + i];
    float invL = 1.f / L;
    int n = qt2*32 + i;
#pragma unroll
    for (int r = 0; r < 8; ++r){
        int c = cgs*8 + r;
        float s = sb2[c];
#pragma unroll
        for (int j = 0; j < 8; ++j) s = fmaf(a1g[j], sw2[c*NQ + j], s);
        s = (s - s2m[c]) * (s2w[c] * rsqrtf(s2v[c] + 1e-5f)) + s2b[c];
        float a2v = fmaxf(s, 0.f);

        // channel -> (ctile, reg, lane-half) in the 32x32 C layout
        int c5   = c & 31;
        int reg  = (c5 & 3) + 4*(c5 >> 3);
        int lsrc = (c5 >> 2) & 1;
        int o    = (c >> 5)*1024 + reg*64 + lsrc*32 + i;
        float O = 0.f;
#pragma unroll
        for (int zz = 0; zz < NSPLIT; ++zz) O += P0[zz*PSLOT + o];
        float pam = gam * O * invL;
        pam = (pam - bnm[c]) * (bnw[c] * rsqrtf(bnv[c] + 1e-5f)) + bnb[c];
        float xv = x[(size_t)(b*C_CH + c)*NPIX + n];
        out[(size_t)(b*C_CH + c)*NPIX + n] = fmaf(xv, a2v, xv + pam);
    }
}

extern "C" void kernel_launch(void* const* d_in, const int* in_sizes, int n_in,
                              void* d_out, int out_size, void* d_ws, size_t ws_size,
                              hipStream_t stream)
{
    const float* x     = (const float*)d_in[0];
    const float* wq    = (const float*)d_in[1];
    const float* bq    = (const float*)d_in[2];
    const float* wk    = (const float*)d_in[3];
    const float* bk    = (const float*)d_in[4];
    const float* wv    = (const float*)d_in[5];
    const float* bv    = (const float*)d_in[6];
    const float* gamma = (const float*)d_in[7];
    const float* bnw   = (const float*)d_in[8];
    const float* bnb   = (const float*)d_in[9];
    const float* bnm   = (const float*)d_in[10];
    const float* bnv   = (const float*)d_in[11];
    const float* sw1   = (const float*)d_in[12];
    const float* sb1   = (const float*)d_in[13];
    const float* s1w   = (const float*)d_in[14];
    const float* s1b   = (const float*)d_in[15];
    const float* s1m   = (const float*)d_in[16];
    const float* s1v   = (const float*)d_in[17];
    const float* sw2   = (const float*)d_in[18];
    const float* sb2   = (const float*)d_in[19];
    const float* s2w   = (const float*)d_in[20];
    const float* s2b   = (const float*)d_in[21];
    const float* s2m   = (const float*)d_in[22];
    const float* s2v   = (const float*)d_in[23];

    size_t off = 0;
    auto give = [&](size_t bytes) -> void* {
        void* r = (char*)d_ws + off;
        off += (bytes + 255) & ~(size_t)255;
        return r;
    };
    __hip_bfloat16* qp   = (__hip_bfloat16*)give((size_t)B_SZ*NPIX*QKS*2);
    __hip_bfloat16* kp   = (__hip_bfloat16*)give((size_t)B_SZ*NPIX*QKS*2);
    __hip_bfloat16* vswz = (__hip_bfloat16*)give((size_t)B_SZ*C_CH*NPIX*2);
    float* amean = (float*)give((size_t)B_SZ*C_CH*4);
    float* pws   = (float*)give((size_t)B_SZ*QBLKS*NSPLIT*PSLOT*4);

    prep_kernel<<<dim3(308), dim3(256), 0, stream>>>(x, wq, bq, wk, bk, wv, bv,
                                                     qp, kp, vswz, amean);
    flash_fused<<<dim3(QBLKS, B_SZ, NSPLIT), dim3(256), 0, stream>>>(qp, kp, vswz, pws);
    combine_kernel<<<dim3(QBLKS, B_SZ), dim3(256), 0, stream>>>(
        pws, amean,
        sw1, sb1, s1w, s1b, s1m, s1v,
        sw2, sb2, s2w, s2b, s2m, s2v,
        x, gamma, bnw, bnb, bnm, bnv, (float*)d_out);
}